// Round 6
// baseline (1091.137 us; speedup 1.0000x reference)
//
#include <hip/hip_runtime.h>
#include <cstdint>
#include <cstddef>

// Problem constants (B,S,HID,NH,IM,E fixed by the reference)
#define B_    4
#define S_    2048
#define HID_  1024
#define NH_   4
#define HD_   256     // HID/NH
#define IM_   2048
#define E_    4
#define M_    8192    // B_*S_ tokens
#define NHG_  4       // heads per attention group

typedef __bf16 bf16x8 __attribute__((ext_vector_type(8)));
typedef float  f32x4  __attribute__((ext_vector_type(4)));

__device__ __forceinline__ unsigned short f32_to_bf16(float f) {
  unsigned int u = __float_as_uint(f);
  u += 0x7fffu + ((u >> 16) & 1u);   // round-to-nearest-even
  return (unsigned short)(u >> 16);
}

// async 16B global->LDS DMA (global_load_lds_dwordx4). LDS dest is
// wave-uniform base + lane*16 -> LDS layout contiguous in lane order.
__device__ __forceinline__ void gload16(const unsigned short* g, unsigned short* l) {
  __builtin_amdgcn_global_load_lds(
      (const __attribute__((address_space(1))) void*)g,
      (__attribute__((address_space(3))) void*)l, 16, 0, 0);
}

template<int N> __device__ __forceinline__ void vwait() {
  if constexpr (N == 0)      asm volatile("s_waitcnt vmcnt(0)" ::: "memory");
  else if constexpr (N == 3) asm volatile("s_waitcnt vmcnt(3)" ::: "memory");
  else                       asm volatile("s_waitcnt vmcnt(4)" ::: "memory");
}

// XCD-aware swizzle: contiguous y-bands per XCD.
__device__ __forceinline__ void swizzle_xy(int& bx, int& by) {
  const int gx = gridDim.x, gy = gridDim.y;
  const int flat = blockIdx.x + blockIdx.y * gx;
  const int xcd = flat & 7, i = flat >> 3;
  const int rpx = gy >> 3;          // y-rows per XCD
  bx = i % gx;
  by = xcd * rpx + i / gx;
}

// ---------------- epilogue variants (generic single-B GEMM) ----------------
#define EPI_F32      0   // C fp32 (attention scores), batched via strideCz
#define EPI_VT       2   // write V^T [b][h][d][s] bf16
#define EPI_PV_O     3   // write attn O into [token][h*HD+n] bf16

struct EpiAux {
  float* c_f32;
  unsigned short* c_bf16;
  long long strideCz;
  int ldc;
};

// Generic batched GEMM: C[z] = A[z] (MxK, row-major, lda) @ B[z]^T.
// 128x128 tile, BK=32, 4 waves x (4x4) 16x16x32 bf16 MFMA fragments.
// Kept for the attention core (scores / PV / V^T) this round.
template<int EPI>
__global__ __launch_bounds__(256) void gemm_bf16k(
    const unsigned short* __restrict__ A, int lda, long long sAo, long long sAi, int zbA,
    const unsigned short* __restrict__ B, int ldb, long long sBo, long long sBi, int zbB,
    int zshift, int zmask, int zbC, int K, EpiAux aux)
{
  __shared__ unsigned short As[2][128 * 32];
  __shared__ unsigned short Bs[2][128 * 32];

  const int t = threadIdx.x;
  int bx, by;
  swizzle_xy(bx, by);
  const int m0 = by * 128, n0 = bx * 128;
  const int z  = blockIdx.z;
  const int zA = z + zbA, zB = z + zbB, zC = z + zbC;
  const unsigned short* Ab = A + (long long)(zA >> zshift) * sAo + (long long)(zA & zmask) * sAi;
  const unsigned short* Bb = B + (long long)(zB >> zshift) * sBo + (long long)(zB & zmask) * sBi;

  const int lane = t & 63, wave = t >> 6;
  const int wm = (wave >> 1) * 64, wn = (wave & 1) * 64;
  const int lrow = lane & 15, quad = lane >> 4;

  f32x4 acc[4][4] = {};

  const int srow = lane >> 2;         // 0..15
  const int sko  = (lane & 3) * 8;    // k-elem 0/8/16/24
  const unsigned short* aRow0 = Ab + (long long)(m0 + wave * 16       + srow) * lda + sko;
  const unsigned short* aRow1 = Ab + (long long)(m0 + (wave + 4) * 16 + srow) * lda + sko;
  const unsigned short* bRow0 = Bb + (long long)(n0 + wave * 16       + srow) * ldb + sko;
  const unsigned short* bRow1 = Bb + (long long)(n0 + (wave + 4) * 16 + srow) * ldb + sko;
  const int dst0 = (wave * 16) * 32, dst1 = ((wave + 4) * 16) * 32;

  gload16(aRow0, &As[0][dst0]);
  gload16(aRow1, &As[0][dst1]);
  gload16(bRow0, &Bs[0][dst0]);
  gload16(bRow1, &Bs[0][dst1]);

  int cur = 0;
  for (int kk = 0; kk < K; kk += 32, cur ^= 1) {
    __syncthreads();
    if (kk + 32 < K) {
      const int nxt = cur ^ 1, k2 = kk + 32;
      gload16(aRow0 + k2, &As[nxt][dst0]);
      gload16(aRow1 + k2, &As[nxt][dst1]);
      gload16(bRow0 + k2, &Bs[nxt][dst0]);
      gload16(bRow1 + k2, &Bs[nxt][dst1]);
    }
    bf16x8 af[4], bfr[4];
    #pragma unroll
    for (int i = 0; i < 4; ++i) {
      af[i]  = *reinterpret_cast<const bf16x8*>(&As[cur][(wm + i * 16 + lrow) * 32 + quad * 8]);
      bfr[i] = *reinterpret_cast<const bf16x8*>(&Bs[cur][(wn + i * 16 + lrow) * 32 + quad * 8]);
    }
    #pragma unroll
    for (int i = 0; i < 4; ++i)
      #pragma unroll
      for (int j = 0; j < 4; ++j)
        acc[i][j] = __builtin_amdgcn_mfma_f32_16x16x32_bf16(af[i], bfr[j], acc[i][j], 0, 0, 0);
  }

  // epilogue: D row = quad*4+r, col = lane&15
  #pragma unroll
  for (int mi = 0; mi < 4; ++mi) {
    #pragma unroll
    for (int ni = 0; ni < 4; ++ni) {
      #pragma unroll
      for (int r = 0; r < 4; ++r) {
        const int gm = m0 + wm + mi * 16 + quad * 4 + r;
        const int gn = n0 + wn + ni * 16 + lrow;
        const float val = acc[mi][ni][r];
        if (EPI == EPI_F32) {
          aux.c_f32[(long long)zC * aux.strideCz + (long long)gm * aux.ldc + gn] = val;
        } else if (EPI == EPI_VT) {
          const int b = gm >> 11, s = gm & (S_ - 1);
          const int h = gn >> 8, d = gn & (HD_ - 1);
          aux.c_bf16[((long long)(b * NH_ + h) * HD_ + d) * S_ + s] = f32_to_bf16(val);
        } else if (EPI == EPI_PV_O) {
          const int b = zC >> 2, h = zC & (NH_ - 1);
          aux.c_bf16[((long long)(b * S_ + gm)) * HID_ + h * HD_ + gn] = f32_to_bf16(val);
        }
      }
    }
  }
}

// =============== gemm7: barrier-light triple-buffered pipeline =============
// BM x 256 tile, BK=32, 512 threads = 8 waves (2M x 4N), per-wave output
// (BM/2) x 64 -> MFR = BM/32 m-frags per wave (r5 BUG was BM/64: half the
// rows never computed). Triple-buffered A and B (BM=256: 96 KiB; BM=128:
// 72 KiB): tile T reads buf[T%3] while tile T+2 stages into buf[(T+2)%3] --
// staging can NEVER overwrite live data, so NO intra-tile barriers exist.
// The only sync is per tile entry: vmcnt(LT) (each wave drains its own
// tile-T DMA loads; counted so T+1's stay in flight, distance = 2 tiles) +
// s_barrier (collective) + sched_barrier(0) (pin: rule #18). Inside the tile
// body plain ds_read + MFMA let the COMPILER emit fine-grained lgkmcnt --
// MFMA overlaps the LDS stream per-wave and across free-running waves.
// WAR safety proof: buf staged at tile T was last ds_read at tile T-1; every
// ds_read feeds an MFMA inside the T-1 body, so it completed before its wave
// reached the tile-T barrier; stage issues after that barrier.
//
// LDS swizzle (BK=32, 64 B rows): logical k-slot q of row r stored at
// physical slot q^(r&3). Write side realized by pre-swizzled global source
// (global_load_lds writes linearly: lane l -> row srow=l>>2, phys slot l&3,
// so lane loads global k-slot (l&3)^(srow&3)). Read: addr = r*64 +
// ((quad^(r&3))<<4). Enumeration: 8 lanes per 16B-class -> conflict-free.
//
// B-row interleave trick (EPI7_QK / EPI7_GU): B matrix rows are interleaved
// in 16-row groups (rows 32k..32k+15 = mat0 cols 16k..16k+15, rows
// 32k+16..32k+31 = mat1 same cols), so acc[mi][2p] / acc[mi][2p+1] are the
// (mat0, mat1) fragments of the SAME output columns -- dual-output GEMM with
// zero cross-lane traffic and single-B LDS cost.
#define EPI7_QK   0   // pairs (q,k): out0=bf16(elu(q)+1), out1=bf16(elu(k)+1)
#define EPI7_GU   1   // pairs (g,u): out0=bf16(silu(g)*u*rw[token][expert])
#define EPI7_WO   2   // o_f32 = acc + add_src
#define EPI7_DOWN 3   // o_f32 += acc
template<int BM, int EPI, int KTOT, int KROW, bool PAIRK>
__global__ __launch_bounds__(512, 2) void gemm7_k(
    const unsigned short* A0, const unsigned short* A1,
    const unsigned short* B0b, const unsigned short* B1b,
    const float* __restrict__ rw, int expert,
    unsigned short* out0, unsigned short* out1,
    float* o_f32, const float* add_src)
{
  constexpr int NT    = KTOT / 32;
  constexpr int NT2   = NT / 2;
  constexpr int AU    = BM / 128;        // A staging units (1 gload/thread each)
  constexpr int AELEM = BM * 32;         // elems per A buffer
  constexpr int LT    = AU + 2;          // DMA loads per tile per thread
  constexpr int MFR   = BM / 32;         // m-frags per wave (BM/2 rows)

  __shared__ unsigned short smem[3 * AELEM + 3 * 8192];

  const int t = threadIdx.x, wave = t >> 6, lane = t & 63;
  const int lrow = lane & 15, quad = lane >> 4;
  const int wrow0 = (wave >> 2) * (BM / 2);
  const int wcol0 = (wave & 3) * 64;

  int bx, by;
  swizzle_xy(bx, by);
  const int m0 = by * BM, n0 = bx * 256;

  // staging sources (pre-swizzled); advance +64 B per staged K-tile
  const int srow = lane >> 2;                       // 0..15
  const int skb  = ((lane & 3) ^ (srow & 3)) << 4;  // swizzled 16B slot
  const char* pA[2]; const char* pB[2]; const char* qA[2]; const char* qB[2];
  #pragma unroll
  for (int u = 0; u < AU; ++u) {
    const int row = m0 + u * 128 + wave * 16 + srow;
    pA[u] = (const char*)(A0 + (size_t)row * KROW) + skb;
    if constexpr (PAIRK) qA[u] = (const char*)(A1 + (size_t)row * KROW) + skb;
  }
  #pragma unroll
  for (int u = 0; u < 2; ++u) {
    const int row = n0 + u * 128 + wave * 16 + srow;
    pB[u] = (const char*)(B0b + (size_t)row * KROW) + skb;
    if constexpr (PAIRK) qB[u] = (const char*)(B1b + (size_t)row * KROW) + skb;
  }

  auto stage = [&](int sb) {
    #pragma unroll
    for (int u = 0; u < AU; ++u) {
      gload16((const unsigned short*)pA[u], &smem[sb * AELEM + u * 4096 + wave * 512]);
      pA[u] += 64;
    }
    #pragma unroll
    for (int u = 0; u < 2; ++u) {
      gload16((const unsigned short*)pB[u], &smem[3 * AELEM + sb * 8192 + u * 4096 + wave * 512]);
      pB[u] += 64;
    }
  };

  // ds_read byte offsets (per-thread constants; buffer base added per tile)
  int roA[MFR], roB[4];
  const int swz = (quad ^ (lrow & 3)) << 4;
  #pragma unroll
  for (int mi = 0; mi < MFR; ++mi)
    roA[mi] = (wrow0 + mi * 16 + lrow) * 64 + swz;
  #pragma unroll
  for (int nj = 0; nj < 4; ++nj)
    roB[nj] = (wcol0 + nj * 16 + lrow) * 64 + swz;

  f32x4 acc[MFR][4] = {};

  stage(0);           // tile 0 -> buf 0
  stage(1);           // tile 1 -> buf 1

  int rd = 0, sb = 2;
  for (int T = 0; T < NT; ++T) {
    if constexpr (PAIRK) {
      if (T + 2 == NT2) {   // switch staging to second K-half matrices
        #pragma unroll
        for (int u = 0; u < AU; ++u) pA[u] = qA[u];
        pB[0] = qB[0]; pB[1] = qB[1];
      }
    }
    // tile-entry sync: tile T's DMA landed everywhere; T+1's stays in flight
    if (T == NT - 1)      vwait<0>();
    else if (LT == 4)     vwait<4>();
    else                  vwait<3>();
    __builtin_amdgcn_s_barrier();
    __builtin_amdgcn_sched_barrier(0);
    if (T + 2 < NT) stage(sb);

    const char* aB = (const char*)smem + rd * (AELEM * 2);
    const char* bB = (const char*)smem + 3 * AELEM * 2 + rd * 16384;
    bf16x8 bf[4];
    #pragma unroll
    for (int nj = 0; nj < 4; ++nj)
      bf[nj] = *(const bf16x8*)(bB + roB[nj]);
    #pragma unroll
    for (int h = 0; h < MFR / 4; ++h) {
      bf16x8 af[4];
      #pragma unroll
      for (int i = 0; i < 4; ++i)
        af[i] = *(const bf16x8*)(aB + roA[h * 4 + i]);
      __builtin_amdgcn_s_setprio(1);
      #pragma unroll
      for (int i = 0; i < 4; ++i)
        #pragma unroll
        for (int nj = 0; nj < 4; ++nj)
          acc[h * 4 + i][nj] =
              __builtin_amdgcn_mfma_f32_16x16x32_bf16(af[i], bf[nj], acc[h * 4 + i][nj], 0, 0, 0);
      __builtin_amdgcn_s_setprio(0);
    }
    if (++rd == 3) rd = 0;
    if (++sb == 3) sb = 0;
  }

  // epilogue: D row = quad*4+r, col lane&15
  #pragma unroll
  for (int mi = 0; mi < MFR; ++mi) {
    #pragma unroll
    for (int r = 0; r < 4; ++r) {
      const int gm = m0 + wrow0 + mi * 16 + quad * 4 + r;
      float rwv = 0.f;
      if (EPI == EPI7_GU) rwv = rw[(size_t)gm * E_ + expert];
      if (EPI == EPI7_QK || EPI == EPI7_GU) {
        #pragma unroll
        for (int pj = 0; pj < 2; ++pj) {
          const int col = ((n0 + wcol0) >> 1) + pj * 16 + lrow;
          const float v0 = acc[mi][2 * pj][r];
          const float v1 = acc[mi][2 * pj + 1][r];
          if (EPI == EPI7_QK) {
            out0[(size_t)gm * HID_ + col] = f32_to_bf16(v0 > 0.f ? v0 + 1.f : __expf(v0));
            out1[(size_t)gm * HID_ + col] = f32_to_bf16(v1 > 0.f ? v1 + 1.f : __expf(v1));
          } else {
            const float sg = v0 / (1.f + __expf(-v0));
            out0[(size_t)gm * IM_ + col] = f32_to_bf16(sg * v1 * rwv);
          }
        }
      } else {
        #pragma unroll
        for (int nj = 0; nj < 4; ++nj) {
          const int gn = n0 + wcol0 + nj * 16 + lrow;
          const size_t idx = (size_t)gm * HID_ + gn;
          if (EPI == EPI7_WO) o_f32[idx] = acc[mi][nj][r] + add_src[idx];
          else                o_f32[idx] += acc[mi][nj][r];
        }
      }
    }
  }
}

// fp32 [R][C] -> bf16 transposed. z=0/1: wq/wk -> qkT with 16-row interleave
// (out row (c>>4)*32 + (c&15) + z*16); z=2 -> vT plain; z=3 -> woT plain.
__global__ void transpose_cast4_k(const float* s0, const float* s1,
                                  const float* s2, const float* s3,
                                  unsigned short* __restrict__ qkT,
                                  unsigned short* __restrict__ vT,
                                  unsigned short* __restrict__ woT, int R, int C)
{
  __shared__ float tile[32][33];
  const int z = blockIdx.z;
  const float* in = (z == 0) ? s0 : (z == 1) ? s1 : (z == 2) ? s2 : s3;
  const int c0 = blockIdx.x * 32, r0 = blockIdx.y * 32;
  const int tx = threadIdx.x, ty = threadIdx.y;
  #pragma unroll
  for (int i = 0; i < 32; i += 8)
    tile[ty + i][tx] = in[(long long)(r0 + ty + i) * C + c0 + tx];
  __syncthreads();
  #pragma unroll
  for (int i = 0; i < 32; i += 8) {
    const int c = c0 + ty + i;
    const unsigned short v = f32_to_bf16(tile[tx][ty + i]);
    if (z < 2) {
      const int orow = ((c >> 4) << 5) + (c & 15) + (z << 4);
      qkT[(long long)orow * R + r0 + tx] = v;
    } else if (z == 2) {
      vT[(long long)c * R + r0 + tx] = v;
    } else {
      woT[(long long)c * R + r0 + tx] = v;
    }
  }
}

// fp32 [R][C] -> bf16 transposed with gate/up 16-row interleave into
// guT[expert][2C][R]: z<4 = gate expert z (parity 0), z>=4 = up (parity 1).
__global__ void transpose_cast2x4_k(const float* __restrict__ sA,
                                    const float* __restrict__ sB,
                                    unsigned short* __restrict__ guT,
                                    int R, int C)
{
  __shared__ float tile[32][33];
  const int z = blockIdx.z;
  const long long eo = (long long)(z & 3) * R * C;
  const float* in = ((z < 4) ? sA : sB) + eo;
  unsigned short* o = guT + (long long)(z & 3) * 2 * R * C;
  const int par16 = (z < 4) ? 0 : 16;
  const int c0 = blockIdx.x * 32, r0 = blockIdx.y * 32;
  const int tx = threadIdx.x, ty = threadIdx.y;
  #pragma unroll
  for (int i = 0; i < 32; i += 8)
    tile[ty + i][tx] = in[(long long)(r0 + ty + i) * C + c0 + tx];
  __syncthreads();
  #pragma unroll
  for (int i = 0; i < 32; i += 8) {
    const int c = c0 + ty + i;
    const int orow = ((c >> 4) << 5) + (c & 15) + par16;
    o[(long long)orow * R + r0 + tx] = f32_to_bf16(tile[tx][ty + i]);
  }
}

// fp32 [R][C] -> bf16 [C][R], batched over z (single base, stride R*C)
__global__ void transpose_cast_k(const float* __restrict__ in,
                                 unsigned short* __restrict__ out, int R, int C)
{
  __shared__ float tile[32][33];
  const long long bo = (long long)blockIdx.z * R * C;
  const int c0 = blockIdx.x * 32, r0 = blockIdx.y * 32;
  const int tx = threadIdx.x, ty = threadIdx.y;
  #pragma unroll
  for (int i = 0; i < 32; i += 8)
    tile[ty + i][tx] = in[bo + (long long)(r0 + ty + i) * C + c0 + tx];
  __syncthreads();
  #pragma unroll
  for (int i = 0; i < 32; i += 8)
    out[bo + (long long)(c0 + ty + i) * R + r0 + tx] = f32_to_bf16(tile[tx][ty + i]);
}

// rmsnorm row (HID=1024) + weight + bf16 cast; one block per token
__global__ __launch_bounds__(256) void rmsnorm_cast_k(
    const float* __restrict__ x, const float* __restrict__ w,
    unsigned short* __restrict__ out)
{
  __shared__ float red[4];
  const int row = blockIdx.x, t = threadIdx.x;
  const float4 v = reinterpret_cast<const float4*>(x + (long long)row * HID_)[t];
  float ss = v.x * v.x + v.y * v.y + v.z * v.z + v.w * v.w;
  #pragma unroll
  for (int off = 32; off > 0; off >>= 1) ss += __shfl_down(ss, off, 64);
  if ((t & 63) == 0) red[t >> 6] = ss;
  __syncthreads();
  ss = red[0] + red[1] + red[2] + red[3];
  const float inv = rsqrtf(ss * (1.0f / HID_) + 1e-6f);
  const float4 wv = reinterpret_cast<const float4*>(w)[t];
  ushort4 o;
  o.x = f32_to_bf16(v.x * inv * wv.x);
  o.y = f32_to_bf16(v.y * inv * wv.y);
  o.z = f32_to_bf16(v.z * inv * wv.z);
  o.w = f32_to_bf16(v.w * inv * wv.w);
  reinterpret_cast<ushort4*>(out + (long long)row * HID_)[t] = o;
}

// softmax over a 2048-wide fp32 row; writes P bf16 IN PLACE over the row
__global__ __launch_bounds__(256) void softmax_rows_k(float* __restrict__ scores)
{
  __shared__ float red[4];
  const long long rbase = ((long long)blockIdx.y * S_ + blockIdx.x) * S_;
  float* row = scores + rbase;
  const int t = threadIdx.x;
  float v[8];
  #pragma unroll
  for (int i = 0; i < 8; ++i) v[i] = row[t + i * 256];
  float m = v[0];
  #pragma unroll
  for (int i = 1; i < 8; ++i) m = fmaxf(m, v[i]);
  #pragma unroll
  for (int off = 32; off > 0; off >>= 1) m = fmaxf(m, __shfl_down(m, off, 64));
  if ((t & 63) == 0) red[t >> 6] = m;
  __syncthreads();
  m = fmaxf(fmaxf(red[0], red[1]), fmaxf(red[2], red[3]));
  __syncthreads();
  float s = 0.f;
  #pragma unroll
  for (int i = 0; i < 8; ++i) { v[i] = __expf(v[i] - m); s += v[i]; }
  #pragma unroll
  for (int off = 32; off > 0; off >>= 1) s += __shfl_down(s, off, 64);
  if ((t & 63) == 0) red[t >> 6] = s;
  __syncthreads();
  const float inv = 1.0f / (red[0] + red[1] + red[2] + red[3]);
  unsigned short* prow = reinterpret_cast<unsigned short*>(scores) + rbase * 2;
  #pragma unroll
  for (int i = 0; i < 8; ++i) prow[t + i * 256] = f32_to_bf16(v[i] * inv);
}

// router: fp32 rms(h1)*ln2w @ router_w + b, softmax over E=4. One wave/token.
__global__ __launch_bounds__(256) void router_k(
    const float* __restrict__ h1, const float* __restrict__ ln2w,
    const float* __restrict__ rwgt, const float* __restrict__ rbias,
    float* __restrict__ rw)
{
  const int wv = threadIdx.x >> 6, lane = threadIdx.x & 63;
  const long long m = (long long)blockIdx.x * 4 + wv;
  const float* xr = h1 + m * HID_;
  float xv[16];
  float ss = 0.f;
  #pragma unroll
  for (int i = 0; i < 16; ++i) { xv[i] = xr[lane + i * 64]; ss += xv[i] * xv[i]; }
  #pragma unroll
  for (int off = 32; off > 0; off >>= 1) ss += __shfl_down(ss, off, 64);
  ss = __shfl(ss, 0, 64);
  const float inv = rsqrtf(ss * (1.0f / HID_) + 1e-6f);
  float l0 = 0, l1 = 0, l2 = 0, l3 = 0;
  #pragma unroll
  for (int i = 0; i < 16; ++i) {
    const int k = lane + i * 64;
    const float xn = xv[i] * inv * ln2w[k];
    const float4 wr = reinterpret_cast<const float4*>(rwgt)[k];
    l0 += xn * wr.x; l1 += xn * wr.y; l2 += xn * wr.z; l3 += xn * wr.w;
  }
  #pragma unroll
  for (int off = 32; off > 0; off >>= 1) {
    l0 += __shfl_down(l0, off, 64);
    l1 += __shfl_down(l1, off, 64);
    l2 += __shfl_down(l2, off, 64);
    l3 += __shfl_down(l3, off, 64);
  }
  if (lane == 0) {
    l0 += rbias[0]; l1 += rbias[1]; l2 += rbias[2]; l3 += rbias[3];
    const float mx = fmaxf(fmaxf(l0, l1), fmaxf(l2, l3));
    const float e0 = __expf(l0 - mx), e1 = __expf(l1 - mx);
    const float e2 = __expf(l2 - mx), e3 = __expf(l3 - mx);
    const float is = 1.0f / (e0 + e1 + e2 + e3);
    reinterpret_cast<float4*>(rw)[m] = make_float4(e0 * is, e1 * is, e2 * is, e3 * is);
  }
}

// balance loss: single block, deterministic
__global__ __launch_bounds__(256) void balance_k(const float* __restrict__ rw,
                                                 float* __restrict__ out_scalar)
{
  __shared__ float red[4];
  float acc = 0.f;
  for (int it = threadIdx.x; it < S_ * E_; it += 256) {
    const int s = it >> 2, e = it & 3;
    float mr = 0.f;
    #pragma unroll
    for (int b = 0; b < B_; ++b) mr += rw[((long long)b * S_ + s) * E_ + e];
    mr *= (1.0f / B_);
    const float d = mr - 1.0f / E_;
    acc += d * d;
  }
  #pragma unroll
  for (int off = 32; off > 0; off >>= 1) acc += __shfl_down(acc, off, 64);
  if ((threadIdx.x & 63) == 0) red[threadIdx.x >> 6] = acc;
  __syncthreads();
  if (threadIdx.x == 0)
    out_scalar[0] = (red[0] + red[1] + red[2] + red[3]) * (0.01f / (S_ * E_));
}

extern "C" void kernel_launch(void* const* d_in, const int* in_sizes, int n_in,
                              void* d_out, int out_size, void* d_ws, size_t ws_size,
                              hipStream_t stream)
{
  const float* hidden   = (const float*)d_in[0];
  const float* ln1w     = (const float*)d_in[1];
  const float* wq       = (const float*)d_in[2];
  const float* wk       = (const float*)d_in[3];
  const float* wv       = (const float*)d_in[4];
  const float* wo       = (const float*)d_in[5];
  const float* ln2w     = (const float*)d_in[6];
  const float* router_w = (const float*)d_in[7];
  const float* router_b = (const float*)d_in[8];
  const float* gate_w   = (const float*)d_in[9];
  const float* up_w     = (const float*)d_in[10];
  const float* down_w   = (const float*)d_in[11];
  float* out = (float*)d_out;   // h1 lives here; MoE accumulates in place

  char* ws = (char*)d_ws;
  size_t off = 0;
  auto carve = [&](size_t bytes) {
    off = (off + 255) & ~(size_t)255;
    char* p = ws + off;
    off += bytes;
    return p;
  };
  unsigned short* qkT   = (unsigned short*)carve((size_t)2 * HID_ * HID_ * 2); // 4 MiB (wq|wk interleaved)
  unsigned short* wvT   = (unsigned short*)carve((size_t)HID_ * HID_ * 2);     // 2 MiB
  unsigned short* woT   = (unsigned short*)carve((size_t)HID_ * HID_ * 2);
  unsigned short* x_bf  = (unsigned short*)carve((size_t)M_ * HID_ * 2);    // 16 MiB, reused as o_bf
  unsigned short* qb    = (unsigned short*)carve((size_t)M_ * HID_ * 2);    // 16 MiB, reused as x2_bf
  unsigned short* kb    = (unsigned short*)carve((size_t)M_ * HID_ * 2);    // 16 MiB \ gu0 (32 MiB)
  unsigned short* vT    = (unsigned short*)carve((size_t)M_ * HID_ * 2);    // 16 MiB /
  float*          rwbuf = (float*)carve((size_t)M_ * E_ * 4);               // 128 KiB
  char*           ubase = carve((size_t)NHG_ * S_ * S_ * 4);                // 64 MiB union
  float*          scores = (float*)ubase;
  unsigned short* guT   = (unsigned short*)(ubase);                          // 32 MiB (4 experts x [2*IM][HID])
  unsigned short* downT = (unsigned short*)(ubase + (size_t)32 * 1024 * 1024);
  unsigned short* o_bf  = x_bf;
  unsigned short* x2_bf = qb;
  unsigned short* gu0   = kb;   // spans kb+vT = 32 MiB
  // second 32 MiB buffer: gu of the odd expert (down pair reads both)
  unsigned short* gu1   = (unsigned short*)carve((size_t)M_ * IM_ * 2);     // +32 MiB
  const bool paired = (ws_size >= off);

  const dim3 blk256(256), blk512(512), blkT(32, 8);

  // 1) attention weights: wq/wk -> interleaved qkT; wv/wo -> plain B^T
  transpose_cast4_k<<<dim3(32, 32, 4), blkT, 0, stream>>>(
      wq, wk, wv, wo, qkT, wvT, woT, HID_, HID_);

  // 2) x = bf16(rms(hidden, ln1_w))
  rmsnorm_cast_k<<<M_, blk256, 0, stream>>>(hidden, ln1w, x_bf);

  // 3) Q+K in one gemm7 dispatch (interleaved B, elu+1 epilogue); V via old VT
  gemm7_k<256, EPI7_QK, 1024, 1024, false><<<dim3(8, 32, 1), blk512, 0, stream>>>(
      x_bf, nullptr, qkT, nullptr, nullptr, 0, qb, kb, nullptr, nullptr);
  {
    EpiAux a{}; a.c_bf16 = vT;
    gemm_bf16k<EPI_VT><<<dim3(8, 64, 1), blk256, 0, stream>>>(
        x_bf, HID_, 0, 0, 0, wvT, HID_, 0, 0, 0, 0, 0, 0, HID_, a);
  }

  // 4) attention, NHG_=4 heads per group; scores slab reused per group
  for (int grp = 0; grp < 16 / NHG_; ++grp) {
    EpiAux as{}; as.c_f32 = scores; as.ldc = S_; as.strideCz = (long long)S_ * S_;
    gemm_bf16k<EPI_F32><<<dim3(16, 16, NHG_), blk256, 0, stream>>>(
        qb, HID_, (long long)S_ * HID_, HD_, grp * NHG_,
        kb, HID_, (long long)S_ * HID_, HD_, grp * NHG_,
        2, 3, 0, HD_, as);
    softmax_rows_k<<<dim3(S_, NHG_, 1), blk256, 0, stream>>>(scores);
    EpiAux ap{}; ap.c_bf16 = o_bf;
    gemm_bf16k<EPI_PV_O><<<dim3(2, 16, NHG_), blk256, 0, stream>>>(
        (const unsigned short*)scores, 2 * S_, (long long)S_ * 2 * S_, 0, 0,
        vT, S_, (long long)HD_ * S_, 0, grp * NHG_,
        0, 0, grp * NHG_, S_, ap);
  }

  // 5) MoE weights: gate/up -> interleaved guT; down -> plain B^T
  transpose_cast2x4_k<<<dim3(64, 32, 8), blkT, 0, stream>>>(
      gate_w, up_w, guT, HID_, IM_);
  transpose_cast_k<<<dim3(32, 64, E_), blkT, 0, stream>>>(down_w, downT, IM_, HID_);

  // 6) h1 = hidden + O @ wo (gemm7 BM=128, full-GPU grid)
  gemm7_k<128, EPI7_WO, 1024, 1024, false><<<dim3(4, 64, 1), blk512, 0, stream>>>(
      o_bf, nullptr, woT, nullptr, nullptr, 0, nullptr, nullptr, out, hidden);

  // 7) x2 = bf16(rms(h1, ln2_w)); router (fp32); balance loss scalar
  rmsnorm_cast_k<<<M_, blk256, 0, stream>>>(out, ln2w, x2_bf);
  router_k<<<M_ / 4, blk256, 0, stream>>>(out, ln2w, router_w, router_b, rwbuf);
  balance_k<<<1, blk256, 0, stream>>>(rwbuf, out + (size_t)M_ * HID_);

  // 8) dense MoE: interleaved single-B GU (silu*u*rw fused) per expert;
  //    expert-paired down via PAIRK K-concat (K=4096) when gu1 fits.
  const size_t w2 = (size_t)2 * IM_ * HID_;   // interleaved gu slab per expert
  const size_t wsz = (size_t)IM_ * HID_;
  if (paired) {
    for (int p = 0; p < 2; ++p) {
      const int e0 = 2 * p, e1 = e0 + 1;
      gemm7_k<256, EPI7_GU, 1024, 1024, false><<<dim3(16, 32, 1), blk512, 0, stream>>>(
          x2_bf, nullptr, guT + (size_t)e0 * w2, nullptr,
          rwbuf, e0, gu0, nullptr, nullptr, nullptr);
      gemm7_k<256, EPI7_GU, 1024, 1024, false><<<dim3(16, 32, 1), blk512, 0, stream>>>(
          x2_bf, nullptr, guT + (size_t)e1 * w2, nullptr,
          rwbuf, e1, gu1, nullptr, nullptr, nullptr);
      gemm7_k<128, EPI7_DOWN, 4096, 2048, true><<<dim3(4, 64, 1), blk512, 0, stream>>>(
          gu0, gu1, downT + (size_t)e0 * wsz, downT + (size_t)e1 * wsz,
          nullptr, 0, nullptr, nullptr, out, nullptr);
    }
  } else {
    for (int i = 0; i < E_; ++i) {
      gemm7_k<256, EPI7_GU, 1024, 1024, false><<<dim3(16, 32, 1), blk512, 0, stream>>>(
          x2_bf, nullptr, guT + (size_t)i * w2, nullptr,
          rwbuf, i, gu0, nullptr, nullptr, nullptr);
      gemm7_k<128, EPI7_DOWN, 2048, 2048, false><<<dim3(4, 64, 1), blk512, 0, stream>>>(
          gu0, nullptr, downT + (size_t)i * wsz, nullptr,
          nullptr, 0, nullptr, nullptr, out, nullptr);
    }
  }
}